// Round 2
// baseline (685.874 us; speedup 1.0000x reference)
//
#include <hip/hip_runtime.h>

// OneToOneLinear: out[n] = prod_f sqrt(sigmoid(10*(x[n,f]*w[f]+b[f])))
// sqrt(sigmoid(z)) = rsqrt(1+exp(-z));  prod_f rsqrt(1+e_f) = rsqrt(prod_f (1+e_f))
// exp(-10(x*w+b)) = exp2(x*a + d), a = -10*w*log2(e), d = -10*b*log2(e).
// Overflow of prod -> inf -> v_rsq gives 0; true value < 1e-19 << 5.7e-10 absmax. Safe.
//
// R1 change vs R0: (1) removed __builtin_nontemporal_load — plain global_load_dwordx4
// is the measured-6.29 TB/s path; nt hint is the only unproven element on the byte
// path and input (537MB) exceeds L3 anyway. (2) unroll x4 independent chains.
// (3) (1+e) chain as fmaf(p,e,p).

typedef float vfloat4 __attribute__((ext_vector_type(4)));

__device__ __forceinline__ float exp2_hw(float x) {
    float r; asm("v_exp_f32 %0, %1" : "=v"(r) : "v"(x)); return r;   // 2^x
}
__device__ __forceinline__ float rsq_hw(float x) {
    float r; asm("v_rsq_f32 %0, %1" : "=v"(r) : "v"(x)); return r;   // 1/sqrt
}

// Butterfly product over the 16-lane group via ds_swizzle (BitMode:
// offset = xor_mask<<10 | or_mask<<5 | and_mask; and=0x1F stays in 32-lane halves,
// xor<16 never crosses the 16-group boundary).
template <int PAT>
__device__ __forceinline__ float bfly_mul(float p) {
    int q = __builtin_amdgcn_ds_swizzle(__builtin_bit_cast(int, p), PAT);
    return p * __builtin_bit_cast(float, q);
}
__device__ __forceinline__ float group16_prod(float p) {
    p = bfly_mul<0x041F>(p);   // xor 1
    p = bfly_mul<0x081F>(p);   // xor 2
    p = bfly_mul<0x101F>(p);   // xor 4
    p = bfly_mul<0x201F>(p);   // xor 8
    return p;
}

// Per-lane partial product over its 4 columns: prod (1+e_i), 1 add + 3 fma.
__device__ __forceinline__ float row_partial(vfloat4 x,
                                             float a0, float a1, float a2, float a3,
                                             float d0, float d1, float d2, float d3) {
    float e0 = exp2_hw(fmaf(x.x, a0, d0));
    float e1 = exp2_hw(fmaf(x.y, a1, d1));
    float e2 = exp2_hw(fmaf(x.z, a2, d2));
    float e3 = exp2_hw(fmaf(x.w, a3, d3));
    float p = 1.0f + e0;
    p = fmaf(p, e1, p);   // p*(1+e1)
    p = fmaf(p, e2, p);
    p = fmaf(p, e3, p);
    return p;
}

// Row = 64 floats = 16 float4. Lane i loads float4 #(base+i): one wave load
// = 64 x 16B = 1 KiB contiguous = 4 full rows. Lane's column group
// (threadIdx.x & 15) is loop-invariant -> (a,d) coeffs live in registers.
__global__ __launch_bounds__(256) void one2one_prod_kernel(
    const vfloat4* __restrict__ in4, // [N*16]
    const float*   __restrict__ w,   // [64]
    const float*   __restrict__ b,   // [64]
    float*         __restrict__ out, // [N]
    int total_f4)                    // N*16 = 2^25
{
    const float C = -14.4269504088896340736f;  // -10 * log2(e)
    const int grp = threadIdx.x & 15;

    const vfloat4 wv = ((const vfloat4*)w)[grp];
    const vfloat4 bv = ((const vfloat4*)b)[grp];
    const float a0 = C * wv.x, a1 = C * wv.y, a2 = C * wv.z, a3 = C * wv.w;
    const float d0 = C * bv.x, d1 = C * bv.y, d2 = C * bv.z, d3 = C * bv.w;

    const int stride = gridDim.x * blockDim.x;
    int f = blockIdx.x * blockDim.x + threadIdx.x;

    // Unroll x4: four independent load->exp->product->butterfly chains.
    for (; f + 3 * stride < total_f4; f += 4 * stride) {
        vfloat4 x0 = in4[f];
        vfloat4 x1 = in4[f + stride];
        vfloat4 x2 = in4[f + 2 * stride];
        vfloat4 x3 = in4[f + 3 * stride];

        float p0 = row_partial(x0, a0, a1, a2, a3, d0, d1, d2, d3);
        float p1 = row_partial(x1, a0, a1, a2, a3, d0, d1, d2, d3);
        float p2 = row_partial(x2, a0, a1, a2, a3, d0, d1, d2, d3);
        float p3 = row_partial(x3, a0, a1, a2, a3, d0, d1, d2, d3);

        p0 = group16_prod(p0);
        p1 = group16_prod(p1);
        p2 = group16_prod(p2);
        p3 = group16_prod(p3);

        if (grp == 0) {
            out[f >> 4]                  = rsq_hw(p0);
            out[(f + stride) >> 4]       = rsq_hw(p1);
            out[(f + 2 * stride) >> 4]   = rsq_hw(p2);
            out[(f + 3 * stride) >> 4]   = rsq_hw(p3);
        }
    }
    // Tail (not taken for N=2^21 with this grid: exactly 16 f4/thread).
    for (; f < total_f4; f += stride) {
        vfloat4 x = in4[f];
        float p = row_partial(x, a0, a1, a2, a3, d0, d1, d2, d3);
        p = group16_prod(p);
        if (grp == 0) out[f >> 4] = rsq_hw(p);
    }
}

extern "C" void kernel_launch(void* const* d_in, const int* in_sizes, int n_in,
                              void* d_out, int out_size, void* d_ws, size_t ws_size,
                              hipStream_t stream) {
    const vfloat4* in4 = (const vfloat4*)d_in[0];  // [N,64] fp32
    const float*   w   = (const float*)d_in[1];    // [64]
    const float*   b   = (const float*)d_in[2];    // [64]
    float* out = (float*)d_out;                    // [N]

    const int total_f4 = in_sizes[0] / 4;          // N*16

    const int block = 256;
    const int grid  = 8192;  // 2M threads; 16 f4-passes -> 4 unrolled iters
    hipLaunchKernelGGL(one2one_prod_kernel, dim3(grid), dim3(block), 0, stream,
                       in4, w, b, out, total_f4);
}